// Round 10
// baseline (812.806 us; speedup 1.0000x reference)
//
#include <hip/hip_runtime.h>
#include <hip/hip_bf16.h>
#include <cmath>

typedef unsigned short ushort_t;
typedef __attribute__((ext_vector_type(8))) short short8;
typedef __attribute__((ext_vector_type(4))) float float4_t;

// ---- problem constants ----
static constexpr int BB   = 2;
static constexpr int SS   = 2048;
static constexpr int DIM  = 2048;
static constexpr int HH   = 16;
static constexpr int DN   = 128;
static constexpr int DR   = 64;
static constexpr int CKV  = 512;
static constexpr int QKH  = DN + DR;          // 192
static constexpr int NCAT = HH * QKH + CKV + DR;  // 3648
static constexpr int NPAD = 3712;             // 29 * 128
static constexpr int MM   = BB * SS;          // 4096

static constexpr int VL = 6;                  // V chunks staged in LDS
static constexpr int NCH = 36 + VL;           // total LDS chunks (42)

__device__ __forceinline__ float b2f(ushort_t u) {
  return __uint_as_float(((unsigned)u) << 16);
}
__device__ __forceinline__ ushort_t f2b(float f) {
  unsigned u = __float_as_uint(f);
  u += 0x7FFFu + ((u >> 16) & 1u);
  return (ushort_t)(u >> 16);
}

__device__ __forceinline__ void store_val(ushort_t* p, float v) { *p = f2b(v); }
__device__ __forceinline__ void store_val(float* p, float v)    { *p = v; }

__device__ __forceinline__ void gload16(const ushort_t* g, ushort_t* s) {
  __builtin_amdgcn_global_load_lds(
      (const __attribute__((address_space(1))) unsigned int*)(g),
      (__attribute__((address_space(3))) unsigned int*)(s), 16, 0, 0);
}

// ---------------- conversion kernels ----------------
__global__ void f32_to_bf16_k(const float* __restrict__ in, ushort_t* __restrict__ out, long n) {
  long i = (long)blockIdx.x * blockDim.x + threadIdx.x;
  long stride = (long)gridDim.x * blockDim.x;
  for (; i < n; i += stride) out[i] = f2b(in[i]);
}

__global__ void build_wcat_k(const float* __restrict__ wq, const float* __restrict__ wkva,
                             ushort_t* __restrict__ wcat) {
  const long n = (long)NPAD * DIM;
  long i = (long)blockIdx.x * blockDim.x + threadIdx.x;
  long stride = (long)gridDim.x * blockDim.x;
  for (; i < n; i += stride) {
    int r = (int)(i >> 11);   // DIM = 2048
    float v;
    if (r < HH * QKH)      v = wq[i];
    else if (r < NCAT)     v = wkva[i - (long)(HH * QKH) * DIM];
    else                   v = 0.f;
    wcat[i] = f2b(v);
  }
}

// wkv_b (4096, 512) -> wbT (h, 512, 128) transposed nope part, wbv (h, 128, 512) v part
__global__ void build_wb_k(const float* __restrict__ wkvb, ushort_t* __restrict__ wbT,
                           ushort_t* __restrict__ wbv) {
  const long n = (long)4096 * 512;
  long i = (long)blockIdx.x * blockDim.x + threadIdx.x;
  long stride = (long)gridDim.x * blockDim.x;
  for (; i < n; i += stride) {
    int c  = (int)(i & 511);
    int rr = (int)(i >> 9);
    int h = rr >> 8, d = rr & 255;
    ushort_t v = f2b(wkvb[i]);
    if (d < DN) wbT[((long)h * CKV + c) * DN + d] = v;
    else        wbv[((long)h * DN + (d - DN)) * CKV + c] = v;
  }
}

// ---------------- GEMM: C(M,N) = A(M,K) @ W(N,K)^T ----------------
// m97 structure: 128x128 tile, BK=32, global_load_lds width-16 staging, 2 barriers/K-step.
template <typename OutT>
__global__ __launch_bounds__(256, 2)
void gemm_bt(const ushort_t* __restrict__ A, const ushort_t* __restrict__ Bw,
             OutT* __restrict__ C, int K, int lda, int ldb, int ldc,
             long aZ, long bZ, long cZ) {
  A  += (long)blockIdx.z * aZ;
  Bw += (long)blockIdx.z * bZ;
  C  += (long)blockIdx.z * cZ;
  __shared__ ushort_t As[128 * 32];
  __shared__ ushort_t Bs[128 * 32];
  const int tid = threadIdx.x;
  const int l = tid & 63, w = tid >> 6;
  const int wr = w >> 1, wc = w & 1;
  const int m0 = blockIdx.x * 128, n0 = blockIdx.y * 128;
  const int lr = tid >> 2;            // 0..63 (row within 64-row half)
  const int lc = (tid & 3) << 3;      // 0,8,16,24
  const int fr = l & 15;              // fragment row
  const int fk = (l >> 4) << 3;       // fragment k offset

  const ushort_t* aSrc = A + (long)(m0 + lr) * lda + lc;
  const ushort_t* bSrc = Bw + (long)(n0 + lr) * ldb + lc;
  ushort_t* asDst0 = &As[w * 512];          // wave-uniform LDS bases (+ lane*16B by HW)
  ushort_t* asDst1 = &As[2048 + w * 512];
  ushort_t* bsDst0 = &Bs[w * 512];
  ushort_t* bsDst1 = &Bs[2048 + w * 512];

  const float4_t zero = {0.f, 0.f, 0.f, 0.f};
  float4_t acc[4][4];
#pragma unroll
  for (int mi = 0; mi < 4; mi++)
#pragma unroll
    for (int ni = 0; ni < 4; ni++) acc[mi][ni] = zero;

  for (int k0 = 0; k0 < K; k0 += 32) {
    __syncthreads();
    gload16(aSrc + k0, asDst0);
    gload16(aSrc + (long)64 * lda + k0, asDst1);
    gload16(bSrc + k0, bsDst0);
    gload16(bSrc + (long)64 * ldb + k0, bsDst1);
    __syncthreads();
    short8 af[4], bf[4];
#pragma unroll
    for (int i = 0; i < 4; i++) af[i] = *(const short8*)&As[(wr * 64 + i * 16 + fr) * 32 + fk];
#pragma unroll
    for (int i = 0; i < 4; i++) bf[i] = *(const short8*)&Bs[(wc * 64 + i * 16 + fr) * 32 + fk];
#pragma unroll
    for (int mi = 0; mi < 4; mi++)
#pragma unroll
      for (int ni = 0; ni < 4; ni++)
        acc[mi][ni] = __builtin_amdgcn_mfma_f32_16x16x32_bf16(af[mi], bf[ni], acc[mi][ni], 0, 0, 0);
  }

  const int rr = (l >> 4) << 2;
#pragma unroll
  for (int mi = 0; mi < 4; mi++)
#pragma unroll
    for (int ni = 0; ni < 4; ni++)
#pragma unroll
      for (int r = 0; r < 4; r++) {
        int row = m0 + wr * 64 + mi * 16 + rr + r;
        int col = n0 + wc * 64 + ni * 16 + fr;
        store_val(&C[(long)row * ldc + col], acc[mi][ni][r]);
      }
}

// ---------------- postproc: RoPE + RMSNorm + reorders ----------------
__global__ __launch_bounds__(256)
void postproc_k(const ushort_t* __restrict__ Y, const float* __restrict__ fcos,
                const float* __restrict__ fsin, const float* __restrict__ kvw,
                ushort_t* __restrict__ qnope, ushort_t* __restrict__ qpe,
                ushort_t* __restrict__ Kext) {
  const int m = blockIdx.x;        // 0..4095  (b*2048 + s)
  const int s = m & (SS - 1);
  const int t = threadIdx.x;       // 0..255
  const ushort_t* Yr = Y + (long)m * NPAD;

  float v0 = b2f(Yr[3072 + t]);
  float v1 = b2f(Yr[3328 + t]);
  float ss = v0 * v0 + v1 * v1;
#pragma unroll
  for (int off = 32; off >= 1; off >>= 1) ss += __shfl_xor(ss, off, 64);
  __shared__ float red[4];
  if ((t & 63) == 0) red[t >> 6] = ss;
  __syncthreads();
  float tot = red[0] + red[1] + red[2] + red[3];
  float rinv = rsqrtf(tot * (1.f / 512.f) + 1e-6f);

  ushort_t* Kr = Kext + (long)m * 576;
  Kr[t]       = f2b(v0 * rinv * kvw[t]);
  Kr[256 + t] = f2b(v1 * rinv * kvw[256 + t]);

  if (t < 32) {  // k_pe rope
    float x0 = b2f(Yr[3584 + 2 * t]);
    float x1 = b2f(Yr[3585 + 2 * t]);
    float c = fcos[s * 32 + t], sn = fsin[s * 32 + t];
    Kr[512 + 2 * t]     = f2b(x0 * c - x1 * sn);
    Kr[512 + 2 * t + 1] = f2b(x0 * sn + x1 * c);
  }

#pragma unroll
  for (int i = 0; i < 8; i++) {
    int idx = t + i * 256;       // 0..2047
    int h = idx >> 7, d = idx & 127;
    qnope[((long)h * MM + m) * DN + d] = Yr[h * QKH + d];
  }
#pragma unroll
  for (int i = 0; i < 2; i++) {
    int p = t + i * 256;         // 0..511
    int h = p >> 5, j = p & 31;
    float x0 = b2f(Yr[h * QKH + DN + 2 * j]);
    float x1 = b2f(Yr[h * QKH + DN + 2 * j + 1]);
    float c = fcos[s * 32 + j], sn = fsin[s * 32 + j];
    qpe[((long)h * MM + m) * DR + 2 * j]     = f2b(x0 * c - x1 * sn);
    qpe[((long)h * MM + m) * DR + 2 * j + 1] = f2b(x0 * sn + x1 * c);
  }
}

// ---------------- Kf retile (lane-major fragment chunks) ----------------
// chunk (b, it, c): elem[l*8+j] = Kext[b*S + it*16 + (l&15)][c*32 + (l>>4)*8 + j]
__global__ __launch_bounds__(256)
void retile_k_k(const ushort_t* __restrict__ Kext, ushort_t* __restrict__ Kf) {
  int w = blockIdx.x * 1024 + threadIdx.x;
#pragma unroll
  for (int i = 0; i < 4; i++, w += 256) {
    int l = w & 63;
    int chunk = w >> 6;
    int c = chunk % 18;
    int rest = chunk / 18;
    int it = rest & 127, b = rest >> 7;
    short8 v = *(const short8*)(Kext + ((long)((b << 11) + (it << 4) + (l & 15))) * 576 +
                                c * 32 + (l >> 4) * 8);
    *(short8*)(Kf + (long)w * 8) = v;
  }
}

// ---------------- Vf (lane-major fragment chunks of V^T) ----------------
// chunk (b, jt, nc): elem[l*8+j] = Kext[b*S + jt*32 + (l>>4)*8 + j][nc*16 + (l&15)]
__global__ __launch_bounds__(256)
void transpose_vf_k(const ushort_t* __restrict__ Kext, ushort_t* __restrict__ Vf) {
  __shared__ ushort_t T[64][66];   // [c_local][t_local]
  const int t0 = blockIdx.x * 64, c0 = blockIdx.y * 64, b = blockIdx.z;
  const int tid = threadIdx.x;
#pragma unroll
  for (int i = 0; i < 2; i++) {
    int ch = tid + i * 256;
    int r = ch >> 3, c8 = (ch & 7) << 3;
    short8 v = *(const short8*)(Kext + ((long)(b * SS + t0 + r)) * 576 + c0 + c8);
#pragma unroll
    for (int j = 0; j < 8; j++) T[c8 + j][r] = (ushort_t)v[j];
  }
  __syncthreads();
#pragma unroll
  for (int i = 0; i < 2; i++) {
    int p = tid + i * 256;
    int jt2 = p >> 8, nc2 = (p >> 6) & 3, l = p & 63;
    short8 v;
#pragma unroll
    for (int j = 0; j < 8; j++) v[j] = (short)T[nc2 * 16 + (l & 15)][jt2 * 32 + (l >> 4) * 8 + j];
    long jt = (t0 >> 5) + jt2, nc = (c0 >> 4) + nc2;
    *(short8*)(Vf + (((long)b * 64 + jt) * 32 + nc) * 512 + l * 8) = v;
  }
}

// ---------------- flash attention v9: hybrid LDS + L2 B-fragment sourcing ----------------
// grid (256, 2): x encodes (b, qp swizzle), y = head-group. 512 threads = 8 waves.
// K (36 chunks) + first VL V-chunks staged in LDS (42 KB -> 3 blocks/CU);
// remaining 32-VL V-chunks read per-wave from L2-resident Vf (coalesced 1KB loads).
__global__ __launch_bounds__(512, 2)
void attn9_k(const ushort_t* __restrict__ qabs, const ushort_t* __restrict__ qpe,
             const ushort_t* __restrict__ Kf, const ushort_t* __restrict__ Vf,
             ushort_t* __restrict__ O, float scale2) {
  __shared__ ushort_t KV[NCH * 512];      // 36 K-chunks + VL V-chunks, 1KB each
  __shared__ ushort_t Pl[8][640];

  const int v = blockIdx.x;
  const int b = v & 1;                    // b == XCD parity: one batch per XCD
  const int x4 = (v >> 1) & 3;
  const int j = v >> 3;
  const int qp = (j < 16) ? (127 - x4 * 16 - j) : (x4 * 16 + j - 16);  // long first, balanced
  const int hg = blockIdx.y;

  const int tid = threadIdx.x, w = tid >> 6, l = tid & 63;
  const int fr = l & 15;
  const int kg = l >> 4;
  const int h = hg * 8 + w;
  const int wq0 = qp * 16;

  // Q fragments (per wave's head)
  const long qrow = (long)b * SS + wq0 + fr;
  const ushort_t* qa = qabs + ((long)h * MM + qrow) * CKV;
  const ushort_t* qptr = qpe + ((long)h * MM + qrow) * DR;
  short8 af[18];
#pragma unroll
  for (int kk = 0; kk < 16; kk++) af[kk] = *(const short8*)(qa + kk * 32 + kg * 8);
  af[16] = *(const short8*)(qptr + kg * 8);
  af[17] = *(const short8*)(qptr + 32 + kg * 8);

  short8 ones;
#pragma unroll
  for (int jj = 0; jj < 8; jj++) ones[jj] = (short)0x3F80;   // bf16 1.0

  const float4_t zero = {0.f, 0.f, 0.f, 0.f};
  float4_t oacc[33];                       // [32] = row-sum accumulator
#pragma unroll
  for (int nc = 0; nc < 33; nc++) oacc[nc] = zero;
  float mrow[4] = {-1e30f, -1e30f, -1e30f, -1e30f};   // log2-domain running max

  const ushort_t* kfb = Kf + (long)b * (128 * 18 * 512);
  const ushort_t* vfb = Vf + (long)b * (64 * 32 * 512);
  const int nt = (wq0 + 16 + 31) >> 5;

  // stage tile: NCH chunks of 1KB; wave handles chunks w, w+8, ...
  auto stage = [&](int tile) {
    const ushort_t* ks = kfb + (long)(tile * 2) * (18 * 512);
    const ushort_t* vs = vfb + (long)tile * (32 * 512);
#pragma unroll
    for (int i = 0; i < 6; i++) {
      int c = w + i * 8;
      if (c < NCH) {
        const ushort_t* src = (c < 36) ? (ks + c * 512) : (vs + (c - 36) * 512);
        gload16(src + l * 8, &KV[c * 512]);
      }
    }
  };

  for (int tile = 0; tile < nt; tile++) {
    stage(tile);
    __syncthreads();                      // staged writes visible to all waves
    const int t0 = tile * 32;
    const ushort_t* vg = vfb + (long)tile * (32 * 512) + l * 8;   // global V base

    // ---- QK^T from LDS (linear ds_read_b128) ----
    float4_t sc[2] = {zero, zero};
#pragma unroll
    for (int nf = 0; nf < 2; nf++)
#pragma unroll
      for (int kk = 0; kk < 18; kk++) {
        short8 bfr = *(const short8*)(&KV[(nf * 18 + kk) * 512 + l * 8]);
        sc[nf] = __builtin_amdgcn_mfma_f32_16x16x32_bf16(af[kk], bfr, sc[nf], 0, 0, 0);
      }

    // ---- scale (log2 domain) + causal mask (only tail tiles) ----
    float pm[2][4];
    const bool tail = (t0 + 31 > wq0);
#pragma unroll
    for (int nf = 0; nf < 2; nf++)
#pragma unroll
      for (int r = 0; r < 4; r++) {
        float vv = sc[nf][r] * scale2;
        if (tail) {
          int tg = t0 + nf * 16 + fr;
          int qg = wq0 + kg * 4 + r;
          vv = (tg <= qg) ? vv : -1e30f;
        }
        pm[nf][r] = vv;
      }

    // ---- online softmax, exp2 domain, defer-max (THR = 8 nats = 11.5416 bits) ----
    float alpha[4];
    bool anyresc = false;
#pragma unroll
    for (int r = 0; r < 4; r++) {
      float tm = fmaxf(pm[0][r], pm[1][r]);
#pragma unroll
      for (int offx = 1; offx <= 8; offx <<= 1) tm = fmaxf(tm, __shfl_xor(tm, offx, 64));
      float mnew = (tm <= mrow[r] + 11.5416f) ? mrow[r] : tm;
      if (mnew != mrow[r]) { alpha[r] = exp2f(mrow[r] - mnew); anyresc = true; }
      else alpha[r] = 1.f;
      float p0 = exp2f(pm[0][r] - mnew);
      float p1 = exp2f(pm[1][r] - mnew);
      Pl[w][(kg * 4 + r) * 40 + fr]      = f2b(p0);
      Pl[w][(kg * 4 + r) * 40 + 16 + fr] = f2b(p1);
      mrow[r] = mnew;
    }

    if (__any(anyresc)) {
#pragma unroll
      for (int nc = 0; nc < 33; nc++)
#pragma unroll
        for (int r = 0; r < 4; r++) oacc[nc][r] *= alpha[r];
    }

    // ---- PV: first VL chunks from LDS, rest from L2 (coalesced) + fused row-sum ----
    short8 pa = *(const short8*)&Pl[w][fr * 40 + kg * 8];
#pragma unroll
    for (int nc = 0; nc < 32; nc++) {
      short8 bv;
      if (nc < VL) bv = *(const short8*)(&KV[(36 + nc) * 512 + l * 8]);
      else         bv = *(const short8*)(vg + nc * 512);
      oacc[nc] = __builtin_amdgcn_mfma_f32_16x16x32_bf16(pa, bv, oacc[nc], 0, 0, 0);
    }
    oacc[32] = __builtin_amdgcn_mfma_f32_16x16x32_bf16(pa, ones, oacc[32], 0, 0, 0);

    __syncthreads();                      // all LDS reads done before next stage overwrites
  }

  // ---- epilogue: LDS transpose in 128-col quarters -> coalesced O stores ----
  float invl[4];
#pragma unroll
  for (int r = 0; r < 4; r++) invl[r] = 1.f / oacc[32][r];
  ushort_t* KV0 = &KV[0];
  ushort_t* obase = O + ((long)h * MM + (long)b * SS + wq0) * CKV;
#pragma unroll
  for (int hh = 0; hh < 4; hh++) {
    __syncthreads();
#pragma unroll
    for (int nc2 = 0; nc2 < 8; nc2++) {
      int nc = hh * 8 + nc2;
#pragma unroll
      for (int r = 0; r < 4; r++)
        KV0[w * 2048 + (kg * 4 + r) * 128 + nc2 * 16 + fr] = f2b(oacc[nc][r] * invl[r]);
    }
    __syncthreads();
#pragma unroll
    for (int i = 0; i < 4; i++) {
      int ch = i * 64 + l;               // 0..255 chunk of 8 within quarter
      int row = ch >> 4;                 // 0..15
      int c8 = (ch & 15) * 8;            // 0..120
      short8 vv = *(const short8*)&KV0[w * 2048 + row * 128 + c8];
      *(short8*)(obase + (long)row * CKV + hh * 128 + c8) = vv;
    }
  }
}

// ---------------- launch ----------------
extern "C" void kernel_launch(void* const* d_in, const int* in_sizes, int n_in,
                              void* d_out, int out_size, void* d_ws, size_t ws_size,
                              hipStream_t stream) {
  const float* x    = (const float*)d_in[0];
  const float* fcos = (const float*)d_in[2];
  const float* fsin = (const float*)d_in[3];
  const float* wq   = (const float*)d_in[4];
  const float* wkva = (const float*)d_in[5];
  const float* kvw  = (const float*)d_in[6];
  const float* wkvb = (const float*)d_in[7];
  const float* wo   = (const float*)d_in[8];
  float* out = (float*)d_out;
  char* ws = (char*)d_ws;

  const size_t O_WCAT = 0;
  const size_t O_WBT  = O_WCAT + (size_t)NPAD * DIM * 2;
  const size_t O_WBV  = O_WBT + (size_t)HH * CKV * DN * 2;
  const size_t O_WO   = O_WBV + (size_t)HH * DN * CKV * 2;
  const size_t O_KEXT = O_WO + (size_t)DIM * DIM * 2;
  const size_t O_QABS = O_KEXT + (size_t)MM * 576 * 2;
  const size_t O_QPE  = O_QABS + (size_t)HH * MM * CKV * 2;
  const size_t O_O2   = O_QPE + (size_t)HH * MM * DR * 2;
  const size_t O_T    = O_O2 + (size_t)MM * DIM * 2;
  const size_t O_Y    = O_T + (size_t)MM * DIM * 2;

  const size_t KF_BYTES = (size_t)BB * 128 * 18 * 512 * 2;   // 4.72 MB

  ushort_t* wcat  = (ushort_t*)(ws + O_WCAT);
  ushort_t* kf    = (ushort_t*)(ws + O_WCAT);              // overlays wcat (dead after G1)
  ushort_t* vf    = (ushort_t*)(ws + O_WCAT + KF_BYTES);   // overlays wcat too
  ushort_t* wbT   = (ushort_t*)(ws + O_WBT);
  ushort_t* wbv   = (ushort_t*)(ws + O_WBV);
  ushort_t* wo_b  = (ushort_t*)(ws + O_WO);
  ushort_t* kext  = (ushort_t*)(ws + O_KEXT);
  ushort_t* qabs  = (ushort_t*)(ws + O_QABS);
  ushort_t* qpe   = (ushort_t*)(ws + O_QPE);
  ushort_t* o2    = (ushort_t*)(ws + O_O2);
  ushort_t* xb    = (ushort_t*)(ws + O_T);      // transient
  ushort_t* qnope = (ushort_t*)(ws + O_T);      // reuses xb
  ushort_t* oatt  = (ushort_t*)(ws + O_T);      // reuses xb+Y
  ushort_t* Y     = (ushort_t*)(ws + O_Y);

  double msc = 0.1 * log(40.0) + 1.0;
  float scale = (float)(pow((double)QKH, -0.5) * msc * msc);
  float scale2 = scale * 1.4426950408889634f;   // log2(e) folded in

  dim3 blk(256);
  f32_to_bf16_k<<<dim3(4096), blk, 0, stream>>>(x, xb, (long)MM * DIM);
  build_wcat_k<<<dim3(4096), blk, 0, stream>>>(wq, wkva, wcat);
  build_wb_k<<<dim3(1024), blk, 0, stream>>>(wkvb, wbT, wbv);
  f32_to_bf16_k<<<dim3(2048), blk, 0, stream>>>(wo, wo_b, (long)DIM * DIM);

  // G1: Y = x @ [wq; wkv_a]^T
  gemm_bt<ushort_t><<<dim3(32, 29, 1), blk, 0, stream>>>(
      xb, wcat, Y, DIM, DIM, DIM, NPAD, 0, 0, 0);

  postproc_k<<<dim3(MM), blk, 0, stream>>>(Y, fcos, fsin, kvw, qnope, qpe, kext);

  // fragment-retile K and V (overlay dead wcat)
  retile_k_k<<<dim3(288), blk, 0, stream>>>(kext, kf);
  transpose_vf_k<<<dim3(SS / 64, CKV / 64, BB), blk, 0, stream>>>(kext, vf);

  // G2: qabs[h] = qnope[h] @ wbT[h]^T
  gemm_bt<ushort_t><<<dim3(32, 4, HH), blk, 0, stream>>>(
      qnope, wbT, qabs, DN, DN, DN, CKV,
      (long)MM * DN, (long)CKV * DN, (long)MM * CKV);

  attn9_k<<<dim3(256, 2), dim3(512), 0, stream>>>(qabs, qpe, kf, vf, oatt, scale2);

  // G4
  gemm_bt<ushort_t><<<dim3(32, 1, HH), blk, 0, stream>>>(
      oatt, wbv, o2, CKV, CKV, CKV, DIM,
      (long)MM * CKV, (long)DN * CKV, (long)DN);

  // G5
  gemm_bt<float><<<dim3(32, 16, 1), blk, 0, stream>>>(
      o2, wo_b, out, DIM, DIM, DIM, DIM, 0, 0, 0);
}

// Round 11
// 500.952 us; speedup vs baseline: 1.6225x; 1.6225x over previous
//
#include <hip/hip_runtime.h>
#include <hip/hip_bf16.h>
#include <cmath>

typedef unsigned short ushort_t;
typedef __attribute__((ext_vector_type(8))) short short8;
typedef __attribute__((ext_vector_type(4))) float float4_t;

// ---- problem constants ----
static constexpr int BB   = 2;
static constexpr int SS   = 2048;
static constexpr int DIM  = 2048;
static constexpr int HH   = 16;
static constexpr int DN   = 128;
static constexpr int DR   = 64;
static constexpr int CKV  = 512;
static constexpr int QKH  = DN + DR;          // 192
static constexpr int NCAT = HH * QKH + CKV + DR;  // 3648
static constexpr int NPAD = 3712;             // 29 * 128
static constexpr int MM   = BB * SS;          // 4096

__device__ __forceinline__ float b2f(ushort_t u) {
  return __uint_as_float(((unsigned)u) << 16);
}
__device__ __forceinline__ ushort_t f2b(float f) {
  unsigned u = __float_as_uint(f);
  u += 0x7FFFu + ((u >> 16) & 1u);
  return (ushort_t)(u >> 16);
}

__device__ __forceinline__ void store_val(ushort_t* p, float v) { *p = f2b(v); }
__device__ __forceinline__ void store_val(float* p, float v)    { *p = v; }

__device__ __forceinline__ void gload16(const ushort_t* g, ushort_t* s) {
  __builtin_amdgcn_global_load_lds(
      (const __attribute__((address_space(1))) unsigned int*)(g),
      (__attribute__((address_space(3))) unsigned int*)(s), 16, 0, 0);
}

// ---------------- conversion kernels ----------------
__global__ void f32_to_bf16_k(const float* __restrict__ in, ushort_t* __restrict__ out, long n) {
  long i = (long)blockIdx.x * blockDim.x + threadIdx.x;
  long stride = (long)gridDim.x * blockDim.x;
  for (; i < n; i += stride) out[i] = f2b(in[i]);
}

__global__ void build_wcat_k(const float* __restrict__ wq, const float* __restrict__ wkva,
                             ushort_t* __restrict__ wcat) {
  const long n = (long)NPAD * DIM;
  long i = (long)blockIdx.x * blockDim.x + threadIdx.x;
  long stride = (long)gridDim.x * blockDim.x;
  for (; i < n; i += stride) {
    int r = (int)(i >> 11);   // DIM = 2048
    float v;
    if (r < HH * QKH)      v = wq[i];
    else if (r < NCAT)     v = wkva[i - (long)(HH * QKH) * DIM];
    else                   v = 0.f;
    wcat[i] = f2b(v);
  }
}

// wkv_b (4096, 512) -> wbT (h, 512, 128) transposed nope part, wbv (h, 128, 512) v part
__global__ void build_wb_k(const float* __restrict__ wkvb, ushort_t* __restrict__ wbT,
                           ushort_t* __restrict__ wbv) {
  const long n = (long)4096 * 512;
  long i = (long)blockIdx.x * blockDim.x + threadIdx.x;
  long stride = (long)gridDim.x * blockDim.x;
  for (; i < n; i += stride) {
    int c  = (int)(i & 511);
    int rr = (int)(i >> 9);
    int h = rr >> 8, d = rr & 255;
    ushort_t v = f2b(wkvb[i]);
    if (d < DN) wbT[((long)h * CKV + c) * DN + d] = v;
    else        wbv[((long)h * DN + (d - DN)) * CKV + c] = v;
  }
}

// ---------------- GEMM: C(M,N) = A(M,K) @ W(N,K)^T ----------------
// m97 structure + XCD-aware block swizzle (T1; bijective since all grids have nwg%8==0).
template <typename OutT>
__global__ __launch_bounds__(256, 2)
void gemm_bt(const ushort_t* __restrict__ A, const ushort_t* __restrict__ Bw,
             OutT* __restrict__ C, int K, int lda, int ldb, int ldc,
             long aZ, long bZ, long cZ) {
  A  += (long)blockIdx.z * aZ;
  Bw += (long)blockIdx.z * bZ;
  C  += (long)blockIdx.z * cZ;
  __shared__ ushort_t As[128 * 32];
  __shared__ ushort_t Bs[128 * 32];
  const int tid = threadIdx.x;
  const int l = tid & 63, w = tid >> 6;
  const int wr = w >> 1, wc = w & 1;

  // XCD swizzle: consecutive post-swizzle ids land on one XCD, sharing B-panels in its L2.
  const int nbx = gridDim.x;
  const int nwg = nbx * gridDim.y;
  int v = blockIdx.y * nbx + blockIdx.x;
  if ((nwg & 7) == 0) v = (v & 7) * (nwg >> 3) + (v >> 3);
  const int m0 = (v % nbx) * 128, n0 = (v / nbx) * 128;

  const int lr = tid >> 2;            // 0..63 (row within 64-row half)
  const int lc = (tid & 3) << 3;      // 0,8,16,24
  const int fr = l & 15;              // fragment row
  const int fk = (l >> 4) << 3;       // fragment k offset

  const ushort_t* aSrc = A + (long)(m0 + lr) * lda + lc;
  const ushort_t* bSrc = Bw + (long)(n0 + lr) * ldb + lc;
  ushort_t* asDst0 = &As[w * 512];          // wave-uniform LDS bases (+ lane*16B by HW)
  ushort_t* asDst1 = &As[2048 + w * 512];
  ushort_t* bsDst0 = &Bs[w * 512];
  ushort_t* bsDst1 = &Bs[2048 + w * 512];

  const float4_t zero = {0.f, 0.f, 0.f, 0.f};
  float4_t acc[4][4];
#pragma unroll
  for (int mi = 0; mi < 4; mi++)
#pragma unroll
    for (int ni = 0; ni < 4; ni++) acc[mi][ni] = zero;

  for (int k0 = 0; k0 < K; k0 += 32) {
    __syncthreads();
    gload16(aSrc + k0, asDst0);
    gload16(aSrc + (long)64 * lda + k0, asDst1);
    gload16(bSrc + k0, bsDst0);
    gload16(bSrc + (long)64 * ldb + k0, bsDst1);
    __syncthreads();
    short8 af[4], bf[4];
#pragma unroll
    for (int i = 0; i < 4; i++) af[i] = *(const short8*)&As[(wr * 64 + i * 16 + fr) * 32 + fk];
#pragma unroll
    for (int i = 0; i < 4; i++) bf[i] = *(const short8*)&Bs[(wc * 64 + i * 16 + fr) * 32 + fk];
#pragma unroll
    for (int mi = 0; mi < 4; mi++)
#pragma unroll
      for (int ni = 0; ni < 4; ni++)
        acc[mi][ni] = __builtin_amdgcn_mfma_f32_16x16x32_bf16(af[mi], bf[ni], acc[mi][ni], 0, 0, 0);
  }

  const int rr = (l >> 4) << 2;
#pragma unroll
  for (int mi = 0; mi < 4; mi++)
#pragma unroll
    for (int ni = 0; ni < 4; ni++)
#pragma unroll
      for (int r = 0; r < 4; r++) {
        int row = m0 + wr * 64 + mi * 16 + rr + r;
        int col = n0 + wc * 64 + ni * 16 + fr;
        store_val(&C[(long)row * ldc + col], acc[mi][ni][r]);
      }
}

// ---------------- postproc: RoPE + RMSNorm + reorders ----------------
__global__ __launch_bounds__(256)
void postproc_k(const ushort_t* __restrict__ Y, const float* __restrict__ fcos,
                const float* __restrict__ fsin, const float* __restrict__ kvw,
                ushort_t* __restrict__ qnope, ushort_t* __restrict__ qpe,
                ushort_t* __restrict__ Kext) {
  const int m = blockIdx.x;        // 0..4095  (b*2048 + s)
  const int s = m & (SS - 1);
  const int t = threadIdx.x;       // 0..255
  const ushort_t* Yr = Y + (long)m * NPAD;

  float v0 = b2f(Yr[3072 + t]);
  float v1 = b2f(Yr[3328 + t]);
  float ss = v0 * v0 + v1 * v1;
#pragma unroll
  for (int off = 32; off >= 1; off >>= 1) ss += __shfl_xor(ss, off, 64);
  __shared__ float red[4];
  if ((t & 63) == 0) red[t >> 6] = ss;
  __syncthreads();
  float tot = red[0] + red[1] + red[2] + red[3];
  float rinv = rsqrtf(tot * (1.f / 512.f) + 1e-6f);

  ushort_t* Kr = Kext + (long)m * 576;
  Kr[t]       = f2b(v0 * rinv * kvw[t]);
  Kr[256 + t] = f2b(v1 * rinv * kvw[256 + t]);

  if (t < 32) {  // k_pe rope
    float x0 = b2f(Yr[3584 + 2 * t]);
    float x1 = b2f(Yr[3585 + 2 * t]);
    float c = fcos[s * 32 + t], sn = fsin[s * 32 + t];
    Kr[512 + 2 * t]     = f2b(x0 * c - x1 * sn);
    Kr[512 + 2 * t + 1] = f2b(x0 * sn + x1 * c);
  }

#pragma unroll
  for (int i = 0; i < 8; i++) {
    int idx = t + i * 256;       // 0..2047
    int h = idx >> 7, d = idx & 127;
    qnope[((long)h * MM + m) * DN + d] = Yr[h * QKH + d];
  }
#pragma unroll
  for (int i = 0; i < 2; i++) {
    int p = t + i * 256;         // 0..511
    int h = p >> 5, j = p & 31;
    float x0 = b2f(Yr[h * QKH + DN + 2 * j]);
    float x1 = b2f(Yr[h * QKH + DN + 2 * j + 1]);
    float c = fcos[s * 32 + j], sn = fsin[s * 32 + j];
    qpe[((long)h * MM + m) * DR + 2 * j]     = f2b(x0 * c - x1 * sn);
    qpe[((long)h * MM + m) * DR + 2 * j + 1] = f2b(x0 * sn + x1 * c);
  }
}

// ---------------- Kf retile (lane-major fragment chunks) ----------------
// chunk (b, it, c): elem[l*8+j] = Kext[b*S + it*16 + (l&15)][c*32 + (l>>4)*8 + j]
__global__ __launch_bounds__(256)
void retile_k_k(const ushort_t* __restrict__ Kext, ushort_t* __restrict__ Kf) {
  int w = blockIdx.x * 1024 + threadIdx.x;
#pragma unroll
  for (int i = 0; i < 4; i++, w += 256) {
    int l = w & 63;
    int chunk = w >> 6;
    int c = chunk % 18;
    int rest = chunk / 18;
    int it = rest & 127, b = rest >> 7;
    short8 v = *(const short8*)(Kext + ((long)((b << 11) + (it << 4) + (l & 15))) * 576 +
                                c * 32 + (l >> 4) * 8);
    *(short8*)(Kf + (long)w * 8) = v;
  }
}

// ---------------- Vf (lane-major fragment chunks of V^T) ----------------
// chunk (b, jt, nc): elem[l*8+j] = Kext[b*S + jt*32 + (l>>4)*8 + j][nc*16 + (l&15)]
__global__ __launch_bounds__(256)
void transpose_vf_k(const ushort_t* __restrict__ Kext, ushort_t* __restrict__ Vf) {
  __shared__ ushort_t T[64][66];   // [c_local][t_local]
  const int t0 = blockIdx.x * 64, c0 = blockIdx.y * 64, b = blockIdx.z;
  const int tid = threadIdx.x;
#pragma unroll
  for (int i = 0; i < 2; i++) {
    int ch = tid + i * 256;
    int r = ch >> 3, c8 = (ch & 7) << 3;
    short8 v = *(const short8*)(Kext + ((long)(b * SS + t0 + r)) * 576 + c0 + c8);
#pragma unroll
    for (int j = 0; j < 8; j++) T[c8 + j][r] = (ushort_t)v[j];
  }
  __syncthreads();
#pragma unroll
  for (int i = 0; i < 2; i++) {
    int p = tid + i * 256;
    int jt2 = p >> 8, nc2 = (p >> 6) & 3, l = p & 63;
    short8 v;
#pragma unroll
    for (int j = 0; j < 8; j++) v[j] = (short)T[nc2 * 16 + (l & 15)][jt2 * 32 + (l >> 4) * 8 + j];
    long jt = (t0 >> 5) + jt2, nc = (c0 >> 4) + nc2;
    *(short8*)(Vf + (((long)b * 64 + jt) * 32 + nc) * 512 + l * 8) = v;
  }
}

// ---------------- flash attention v10: r8 structure + width-16 row reduce ----------------
__global__ __launch_bounds__(512, 2)
void attn10_k(const ushort_t* __restrict__ qabs, const ushort_t* __restrict__ qpe,
              const ushort_t* __restrict__ Kf, const ushort_t* __restrict__ Vf,
              ushort_t* __restrict__ O, float scale2) {
  __shared__ ushort_t KV[68 * 512];       // 36 K-chunks + 32 V-chunks, 1KB each
  __shared__ ushort_t Pl[8][640];

  const int v = blockIdx.x;
  const int b = v & 1;
  const int x4 = (v >> 1) & 3;
  const int j = v >> 3;
  const int qp = (j < 16) ? (127 - x4 * 16 - j) : (x4 * 16 + j - 16);  // long first, XCD-balanced
  const int hg = blockIdx.y;

  const int tid = threadIdx.x, w = tid >> 6, l = tid & 63;
  const int fr = l & 15;
  const int kg = l >> 4;
  const int h = hg * 8 + w;
  const int wq0 = qp * 16;

  // Q fragments (per wave's head)
  const long qrow = (long)b * SS + wq0 + fr;
  const ushort_t* qa = qabs + ((long)h * MM + qrow) * CKV;
  const ushort_t* qptr = qpe + ((long)h * MM + qrow) * DR;
  short8 af[18];
#pragma unroll
  for (int kk = 0; kk < 16; kk++) af[kk] = *(const short8*)(qa + kk * 32 + kg * 8);
  af[16] = *(const short8*)(qptr + kg * 8);
  af[17] = *(const short8*)(qptr + 32 + kg * 8);

  short8 ones;
#pragma unroll
  for (int jj = 0; jj < 8; jj++) ones[jj] = (short)0x3F80;   // bf16 1.0

  const float4_t zero = {0.f, 0.f, 0.f, 0.f};
  float4_t oacc[33];                       // [32] = row-sum accumulator
#pragma unroll
  for (int nc = 0; nc < 33; nc++) oacc[nc] = zero;
  float mrow[4] = {-1e30f, -1e30f, -1e30f, -1e30f};   // log2-domain running max

  const ushort_t* kfb = Kf + (long)b * (128 * 18 * 512);
  const ushort_t* vfb = Vf + (long)b * (64 * 32 * 512);
  const int nt = (wq0 + 16 + 31) >> 5;

  // stage tile: 68 chunks of 1KB; wave handles chunks w, w+8, ...
  auto stage = [&](int tile) {
    const ushort_t* ks = kfb + (long)(tile * 2) * (18 * 512);
    const ushort_t* vs = vfb + (long)tile * (32 * 512);
#pragma unroll
    for (int i = 0; i < 9; i++) {
      int c = w + i * 8;
      if (c < 68) {
        const ushort_t* src = (c < 36) ? (ks + c * 512) : (vs + (c - 36) * 512);
        gload16(src + l * 8, &KV[c * 512]);
      }
    }
  };

  for (int tile = 0; tile < nt; tile++) {
    stage(tile);
    __syncthreads();                      // staged writes visible to all waves
    const int t0 = tile * 32;

    // ---- QK^T from LDS (linear ds_read_b128) ----
    float4_t sc[2] = {zero, zero};
#pragma unroll
    for (int nf = 0; nf < 2; nf++)
#pragma unroll
      for (int kk = 0; kk < 18; kk++) {
        short8 bfr = *(const short8*)(&KV[(nf * 18 + kk) * 512 + l * 8]);
        sc[nf] = __builtin_amdgcn_mfma_f32_16x16x32_bf16(af[kk], bfr, sc[nf], 0, 0, 0);
      }

    // ---- scale (log2 domain) + causal mask (only tail tiles) ----
    float pm[2][4];
    const bool tail = (t0 + 31 > wq0);
#pragma unroll
    for (int nf = 0; nf < 2; nf++)
#pragma unroll
      for (int r = 0; r < 4; r++) {
        float vv = sc[nf][r] * scale2;
        if (tail) {
          int tg = t0 + nf * 16 + fr;
          int qg = wq0 + kg * 4 + r;
          vv = (tg <= qg) ? vv : -1e30f;
        }
        pm[nf][r] = vv;
      }

    // ---- online softmax, exp2 domain, defer-max (THR = 8 nats = 11.5416 bits) ----
    // Row reduce only spans the 16 contiguous fr lanes -> width 16 (DPP-eligible).
    float alpha[4];
    bool anyresc = false;
#pragma unroll
    for (int r = 0; r < 4; r++) {
      float tm = fmaxf(pm[0][r], pm[1][r]);
#pragma unroll
      for (int offx = 1; offx <= 8; offx <<= 1) tm = fmaxf(tm, __shfl_xor(tm, offx, 16));
      float mnew = (tm <= mrow[r] + 11.5416f) ? mrow[r] : tm;
      if (mnew != mrow[r]) { alpha[r] = exp2f(mrow[r] - mnew); anyresc = true; }
      else alpha[r] = 1.f;
      float p0 = exp2f(pm[0][r] - mnew);
      float p1 = exp2f(pm[1][r] - mnew);
      Pl[w][(kg * 4 + r) * 40 + fr]      = f2b(p0);
      Pl[w][(kg * 4 + r) * 40 + 16 + fr] = f2b(p1);
      mrow[r] = mnew;
    }

    if (__any(anyresc)) {
#pragma unroll
      for (int nc = 0; nc < 33; nc++)
#pragma unroll
        for (int r = 0; r < 4; r++) oacc[nc][r] *= alpha[r];
    }

    // ---- PV from LDS V-chunks + fused row-sum ----
    short8 pa = *(const short8*)&Pl[w][fr * 40 + kg * 8];
#pragma unroll
    for (int nc = 0; nc < 32; nc++) {
      short8 bv = *(const short8*)(&KV[(36 + nc) * 512 + l * 8]);
      oacc[nc] = __builtin_amdgcn_mfma_f32_16x16x32_bf16(pa, bv, oacc[nc], 0, 0, 0);
    }
    oacc[32] = __builtin_amdgcn_mfma_f32_16x16x32_bf16(pa, ones, oacc[32], 0, 0, 0);

    __syncthreads();                      // all reads done before next stage overwrites
  }

  // ---- epilogue: LDS transpose -> coalesced O stores ----
  float invl[4];
#pragma unroll
  for (int r = 0; r < 4; r++) invl[r] = 1.f / oacc[32][r];
  ushort_t* KV0 = &KV[0];
  ushort_t* obase = O + ((long)h * MM + (long)b * SS + wq0) * CKV;
#pragma unroll
  for (int hh = 0; hh < 2; hh++) {
    __syncthreads();
#pragma unroll
    for (int nc2 = 0; nc2 < 16; nc2++) {
      int nc = hh * 16 + nc2;
#pragma unroll
      for (int r = 0; r < 4; r++)
        KV0[w * 4096 + (kg * 4 + r) * 256 + nc2 * 16 + fr] = f2b(oacc[nc][r] * invl[r]);
    }
    __syncthreads();
#pragma unroll
    for (int i = 0; i < 8; i++) {
      short8 vv = *(const short8*)&KV0[w * 4096 + i * 512 + l * 8];
      int row = 2 * i + (l >> 5);
      int col = (l & 31) * 8;
      *(short8*)(obase + (long)row * CKV + hh * 256 + col) = vv;
    }
  }
}

// ---------------- launch ----------------
extern "C" void kernel_launch(void* const* d_in, const int* in_sizes, int n_in,
                              void* d_out, int out_size, void* d_ws, size_t ws_size,
                              hipStream_t stream) {
  const float* x    = (const float*)d_in[0];
  const float* fcos = (const float*)d_in[2];
  const float* fsin = (const float*)d_in[3];
  const float* wq   = (const float*)d_in[4];
  const float* wkva = (const float*)d_in[5];
  const float* kvw  = (const float*)d_in[6];
  const float* wkvb = (const float*)d_in[7];
  const float* wo   = (const float*)d_in[8];
  float* out = (float*)d_out;
  char* ws = (char*)d_ws;

  const size_t O_WCAT = 0;
  const size_t O_WBT  = O_WCAT + (size_t)NPAD * DIM * 2;
  const size_t O_WBV  = O_WBT + (size_t)HH * CKV * DN * 2;
  const size_t O_WO   = O_WBV + (size_t)HH * DN * CKV * 2;
  const size_t O_KEXT = O_WO + (size_t)DIM * DIM * 2;
  const size_t O_QABS = O_KEXT + (size_t)MM * 576 * 2;
  const size_t O_QPE  = O_QABS + (size_t)HH * MM * CKV * 2;
  const size_t O_O2   = O_QPE + (size_t)HH * MM * DR * 2;
  const size_t O_T    = O_O2 + (size_t)MM * DIM * 2;
  const size_t O_Y    = O_T + (size_t)MM * DIM * 2;

  const size_t KF_BYTES = (size_t)BB * 128 * 18 * 512 * 2;   // 4.72 MB

  ushort_t* wcat  = (ushort_t*)(ws + O_WCAT);
  ushort_t* kf    = (ushort_t*)(ws + O_WCAT);              // overlays wcat (dead after G1)
  ushort_t* vf    = (ushort_t*)(ws + O_WCAT + KF_BYTES);   // overlays wcat too
  ushort_t* wbT   = (ushort_t*)(ws + O_WBT);
  ushort_t* wbv   = (ushort_t*)(ws + O_WBV);
  ushort_t* wo_b  = (ushort_t*)(ws + O_WO);
  ushort_t* kext  = (ushort_t*)(ws + O_KEXT);
  ushort_t* qabs  = (ushort_t*)(ws + O_QABS);
  ushort_t* qpe   = (ushort_t*)(ws + O_QPE);
  ushort_t* o2    = (ushort_t*)(ws + O_O2);
  ushort_t* xb    = (ushort_t*)(ws + O_T);      // transient
  ushort_t* qnope = (ushort_t*)(ws + O_T);      // reuses xb
  ushort_t* oatt  = (ushort_t*)(ws + O_T);      // reuses xb+Y
  ushort_t* Y     = (ushort_t*)(ws + O_Y);

  double msc = 0.1 * log(40.0) + 1.0;
  float scale = (float)(pow((double)QKH, -0.5) * msc * msc);
  float scale2 = scale * 1.4426950408889634f;   // log2(e) folded in

  dim3 blk(256);
  f32_to_bf16_k<<<dim3(4096), blk, 0, stream>>>(x, xb, (long)MM * DIM);
  build_wcat_k<<<dim3(4096), blk, 0, stream>>>(wq, wkva, wcat);
  build_wb_k<<<dim3(1024), blk, 0, stream>>>(wkvb, wbT, wbv);
  f32_to_bf16_k<<<dim3(2048), blk, 0, stream>>>(wo, wo_b, (long)DIM * DIM);

  // G1: Y = x @ [wq; wkv_a]^T
  gemm_bt<ushort_t><<<dim3(32, 29, 1), blk, 0, stream>>>(
      xb, wcat, Y, DIM, DIM, DIM, NPAD, 0, 0, 0);

  postproc_k<<<dim3(MM), blk, 0, stream>>>(Y, fcos, fsin, kvw, qnope, qpe, kext);

  // fragment-retile K and V (overlay dead wcat)
  retile_k_k<<<dim3(288), blk, 0, stream>>>(kext, kf);
  transpose_vf_k<<<dim3(SS / 64, CKV / 64, BB), blk, 0, stream>>>(kext, vf);

  // G2: qabs[h] = qnope[h] @ wbT[h]^T
  gemm_bt<ushort_t><<<dim3(32, 4, HH), blk, 0, stream>>>(
      qnope, wbT, qabs, DN, DN, DN, CKV,
      (long)MM * DN, (long)CKV * DN, (long)MM * CKV);

  attn10_k<<<dim3(256, 2), dim3(512), 0, stream>>>(qabs, qpe, kf, vf, oatt, scale2);

  // G4
  gemm_bt<ushort_t><<<dim3(32, 1, HH), blk, 0, stream>>>(
      oatt, wbv, o2, CKV, CKV, CKV, DIM,
      (long)MM * CKV, (long)DN * CKV, (long)DN);

  // G5
  gemm_bt<float><<<dim3(32, 16, 1), blk, 0, stream>>>(
      o2, wo_b, out, DIM, DIM, DIM, DIM, 0, 0, 0);
}

// Round 12
// 471.435 us; speedup vs baseline: 1.7241x; 1.0626x over previous
//
#include <hip/hip_runtime.h>
#include <hip/hip_bf16.h>
#include <cmath>

typedef unsigned short ushort_t;
typedef __attribute__((ext_vector_type(8))) short short8;
typedef __attribute__((ext_vector_type(4))) float float4_t;

// ---- problem constants ----
static constexpr int BB   = 2;
static constexpr int SS   = 2048;
static constexpr int DIM  = 2048;
static constexpr int HH   = 16;
static constexpr int DN   = 128;
static constexpr int DR   = 64;
static constexpr int CKV  = 512;
static constexpr int QKH  = DN + DR;          // 192
static constexpr int NCAT = HH * QKH + CKV + DR;  // 3648
static constexpr int NPAD = 3712;             // 29 * 128
static constexpr int MM   = BB * SS;          // 4096

__device__ __forceinline__ float b2f(ushort_t u) {
  return __uint_as_float(((unsigned)u) << 16);
}
__device__ __forceinline__ ushort_t f2b(float f) {
  unsigned u = __float_as_uint(f);
  u += 0x7FFFu + ((u >> 16) & 1u);
  return (ushort_t)(u >> 16);
}

__device__ __forceinline__ void store_val(ushort_t* p, float v) { *p = f2b(v); }
__device__ __forceinline__ void store_val(float* p, float v)    { *p = v; }

__device__ __forceinline__ void gload16(const ushort_t* g, ushort_t* s) {
  __builtin_amdgcn_global_load_lds(
      (const __attribute__((address_space(1))) unsigned int*)(g),
      (__attribute__((address_space(3))) unsigned int*)(s), 16, 0, 0);
}

// ---------------- conversion kernels ----------------
__global__ void f32_to_bf16_k(const float* __restrict__ in, ushort_t* __restrict__ out, long n) {
  long i = (long)blockIdx.x * blockDim.x + threadIdx.x;
  long stride = (long)gridDim.x * blockDim.x;
  for (; i < n; i += stride) out[i] = f2b(in[i]);
}

__global__ void build_wcat_k(const float* __restrict__ wq, const float* __restrict__ wkva,
                             ushort_t* __restrict__ wcat) {
  const long n = (long)NPAD * DIM;
  long i = (long)blockIdx.x * blockDim.x + threadIdx.x;
  long stride = (long)gridDim.x * blockDim.x;
  for (; i < n; i += stride) {
    int r = (int)(i >> 11);   // DIM = 2048
    float v;
    if (r < HH * QKH)      v = wq[i];
    else if (r < NCAT)     v = wkva[i - (long)(HH * QKH) * DIM];
    else                   v = 0.f;
    wcat[i] = f2b(v);
  }
}

// wkv_b (4096, 512) -> wbT (h, 512, 128) transposed nope part, wbv (h, 128, 512) v part
__global__ void build_wb_k(const float* __restrict__ wkvb, ushort_t* __restrict__ wbT,
                           ushort_t* __restrict__ wbv) {
  const long n = (long)4096 * 512;
  long i = (long)blockIdx.x * blockDim.x + threadIdx.x;
  long stride = (long)gridDim.x * blockDim.x;
  for (; i < n; i += stride) {
    int c  = (int)(i & 511);
    int rr = (int)(i >> 9);
    int h = rr >> 8, d = rr & 255;
    ushort_t v = f2b(wkvb[i]);
    if (d < DN) wbT[((long)h * CKV + c) * DN + d] = v;
    else        wbv[((long)h * DN + (d - DN)) * CKV + c] = v;
  }
}

// ---------------- GEMM: C(M,N) = A(M,K) @ W(N,K)^T ----------------
// m97 structure: 128x128 tile, BK=32, global_load_lds width-16 staging, 2 barriers/K-step.
// (XCD swizzle removed: r11 measured it as a ~10us regression on these small grids.)
template <typename OutT>
__global__ __launch_bounds__(256, 2)
void gemm_bt(const ushort_t* __restrict__ A, const ushort_t* __restrict__ Bw,
             OutT* __restrict__ C, int K, int lda, int ldb, int ldc,
             long aZ, long bZ, long cZ) {
  A  += (long)blockIdx.z * aZ;
  Bw += (long)blockIdx.z * bZ;
  C  += (long)blockIdx.z * cZ;
  __shared__ ushort_t As[128 * 32];
  __shared__ ushort_t Bs[128 * 32];
  const int tid = threadIdx.x;
  const int l = tid & 63, w = tid >> 6;
  const int wr = w >> 1, wc = w & 1;
  const int m0 = blockIdx.x * 128, n0 = blockIdx.y * 128;
  const int lr = tid >> 2;            // 0..63 (row within 64-row half)
  const int lc = (tid & 3) << 3;      // 0,8,16,24
  const int fr = l & 15;              // fragment row
  const int fk = (l >> 4) << 3;       // fragment k offset

  const ushort_t* aSrc = A + (long)(m0 + lr) * lda + lc;
  const ushort_t* bSrc = Bw + (long)(n0 + lr) * ldb + lc;
  ushort_t* asDst0 = &As[w * 512];          // wave-uniform LDS bases (+ lane*16B by HW)
  ushort_t* asDst1 = &As[2048 + w * 512];
  ushort_t* bsDst0 = &Bs[w * 512];
  ushort_t* bsDst1 = &Bs[2048 + w * 512];

  const float4_t zero = {0.f, 0.f, 0.f, 0.f};
  float4_t acc[4][4];
#pragma unroll
  for (int mi = 0; mi < 4; mi++)
#pragma unroll
    for (int ni = 0; ni < 4; ni++) acc[mi][ni] = zero;

  for (int k0 = 0; k0 < K; k0 += 32) {
    __syncthreads();
    gload16(aSrc + k0, asDst0);
    gload16(aSrc + (long)64 * lda + k0, asDst1);
    gload16(bSrc + k0, bsDst0);
    gload16(bSrc + (long)64 * ldb + k0, bsDst1);
    __syncthreads();
    short8 af[4], bf[4];
#pragma unroll
    for (int i = 0; i < 4; i++) af[i] = *(const short8*)&As[(wr * 64 + i * 16 + fr) * 32 + fk];
#pragma unroll
    for (int i = 0; i < 4; i++) bf[i] = *(const short8*)&Bs[(wc * 64 + i * 16 + fr) * 32 + fk];
#pragma unroll
    for (int mi = 0; mi < 4; mi++)
#pragma unroll
      for (int ni = 0; ni < 4; ni++)
        acc[mi][ni] = __builtin_amdgcn_mfma_f32_16x16x32_bf16(af[mi], bf[ni], acc[mi][ni], 0, 0, 0);
  }

  const int rr = (l >> 4) << 2;
#pragma unroll
  for (int mi = 0; mi < 4; mi++)
#pragma unroll
    for (int ni = 0; ni < 4; ni++)
#pragma unroll
      for (int r = 0; r < 4; r++) {
        int row = m0 + wr * 64 + mi * 16 + rr + r;
        int col = n0 + wc * 64 + ni * 16 + fr;
        store_val(&C[(long)row * ldc + col], acc[mi][ni][r]);
      }
}

// ---------------- postproc: RoPE + RMSNorm + reorders ----------------
__global__ __launch_bounds__(256)
void postproc_k(const ushort_t* __restrict__ Y, const float* __restrict__ fcos,
                const float* __restrict__ fsin, const float* __restrict__ kvw,
                ushort_t* __restrict__ qnope, ushort_t* __restrict__ qpe,
                ushort_t* __restrict__ Kext) {
  const int m = blockIdx.x;        // 0..4095  (b*2048 + s)
  const int s = m & (SS - 1);
  const int t = threadIdx.x;       // 0..255
  const ushort_t* Yr = Y + (long)m * NPAD;

  float v0 = b2f(Yr[3072 + t]);
  float v1 = b2f(Yr[3328 + t]);
  float ss = v0 * v0 + v1 * v1;
#pragma unroll
  for (int off = 32; off >= 1; off >>= 1) ss += __shfl_xor(ss, off, 64);
  __shared__ float red[4];
  if ((t & 63) == 0) red[t >> 6] = ss;
  __syncthreads();
  float tot = red[0] + red[1] + red[2] + red[3];
  float rinv = rsqrtf(tot * (1.f / 512.f) + 1e-6f);

  ushort_t* Kr = Kext + (long)m * 576;
  Kr[t]       = f2b(v0 * rinv * kvw[t]);
  Kr[256 + t] = f2b(v1 * rinv * kvw[256 + t]);

  if (t < 32) {  // k_pe rope
    float x0 = b2f(Yr[3584 + 2 * t]);
    float x1 = b2f(Yr[3585 + 2 * t]);
    float c = fcos[s * 32 + t], sn = fsin[s * 32 + t];
    Kr[512 + 2 * t]     = f2b(x0 * c - x1 * sn);
    Kr[512 + 2 * t + 1] = f2b(x0 * sn + x1 * c);
  }

#pragma unroll
  for (int i = 0; i < 8; i++) {
    int idx = t + i * 256;       // 0..2047
    int h = idx >> 7, d = idx & 127;
    qnope[((long)h * MM + m) * DN + d] = Yr[h * QKH + d];
  }
#pragma unroll
  for (int i = 0; i < 2; i++) {
    int p = t + i * 256;         // 0..511
    int h = p >> 5, j = p & 31;
    float x0 = b2f(Yr[h * QKH + DN + 2 * j]);
    float x1 = b2f(Yr[h * QKH + DN + 2 * j + 1]);
    float c = fcos[s * 32 + j], sn = fsin[s * 32 + j];
    qpe[((long)h * MM + m) * DR + 2 * j]     = f2b(x0 * c - x1 * sn);
    qpe[((long)h * MM + m) * DR + 2 * j + 1] = f2b(x0 * sn + x1 * c);
  }
}

// ---------------- Kf retile (lane-major fragment chunks) ----------------
// chunk (b, it, c): elem[l*8+j] = Kext[b*S + it*16 + (l&15)][c*32 + (l>>4)*8 + j]
__global__ __launch_bounds__(256)
void retile_k_k(const ushort_t* __restrict__ Kext, ushort_t* __restrict__ Kf) {
  int w = blockIdx.x * 1024 + threadIdx.x;
#pragma unroll
  for (int i = 0; i < 4; i++, w += 256) {
    int l = w & 63;
    int chunk = w >> 6;
    int c = chunk % 18;
    int rest = chunk / 18;
    int it = rest & 127, b = rest >> 7;
    short8 v = *(const short8*)(Kext + ((long)((b << 11) + (it << 4) + (l & 15))) * 576 +
                                c * 32 + (l >> 4) * 8);
    *(short8*)(Kf + (long)w * 8) = v;
  }
}

// ---------------- Vf (lane-major fragment chunks of V^T) ----------------
// chunk (b, jt, nc): elem[l*8+j] = Kext[b*S + jt*32 + (l>>4)*8 + j][nc*16 + (l&15)]
__global__ __launch_bounds__(256)
void transpose_vf_k(const ushort_t* __restrict__ Kext, ushort_t* __restrict__ Vf) {
  __shared__ ushort_t T[64][66];   // [c_local][t_local]
  const int t0 = blockIdx.x * 64, c0 = blockIdx.y * 64, b = blockIdx.z;
  const int tid = threadIdx.x;
#pragma unroll
  for (int i = 0; i < 2; i++) {
    int ch = tid + i * 256;
    int r = ch >> 3, c8 = (ch & 7) << 3;
    short8 v = *(const short8*)(Kext + ((long)(b * SS + t0 + r)) * 576 + c0 + c8);
#pragma unroll
    for (int j = 0; j < 8; j++) T[c8 + j][r] = (ushort_t)v[j];
  }
  __syncthreads();
#pragma unroll
  for (int i = 0; i < 2; i++) {
    int p = tid + i * 256;
    int jt2 = p >> 8, nc2 = (p >> 6) & 3, l = p & 63;
    short8 v;
#pragma unroll
    for (int j = 0; j < 8; j++) v[j] = (short)T[nc2 * 16 + (l & 15)][jt2 * 32 + (l >> 4) * 8 + j];
    long jt = (t0 >> 5) + jt2, nc = (c0 >> 4) + nc2;
    *(short8*)(Vf + (((long)b * 64 + jt) * 32 + nc) * 512 + l * 8) = v;
  }
}

// ---------------- flash attention v11: vote-guarded lazy max reduce ----------------
// r8 structure (single-buffered KV, 8 heads/block). Common path: no cross-lane
// reduce -- 8 compares + __any; full shfl reduce + rescale only on trigger.
__global__ __launch_bounds__(512, 2)
void attn11_k(const ushort_t* __restrict__ qabs, const ushort_t* __restrict__ qpe,
              const ushort_t* __restrict__ Kf, const ushort_t* __restrict__ Vf,
              ushort_t* __restrict__ O, float scale2) {
  __shared__ ushort_t KV[68 * 512];       // 36 K-chunks + 32 V-chunks, 1KB each
  __shared__ ushort_t Pl[8][640];

  const int v = blockIdx.x;
  const int b = v & 1;
  const int x4 = (v >> 1) & 3;
  const int j = v >> 3;
  const int qp = (j < 16) ? (127 - x4 * 16 - j) : (x4 * 16 + j - 16);  // long first, XCD-balanced
  const int hg = blockIdx.y;

  const int tid = threadIdx.x, w = tid >> 6, l = tid & 63;
  const int fr = l & 15;
  const int kg = l >> 4;
  const int h = hg * 8 + w;
  const int wq0 = qp * 16;

  // Q fragments (per wave's head)
  const long qrow = (long)b * SS + wq0 + fr;
  const ushort_t* qa = qabs + ((long)h * MM + qrow) * CKV;
  const ushort_t* qptr = qpe + ((long)h * MM + qrow) * DR;
  short8 af[18];
#pragma unroll
  for (int kk = 0; kk < 16; kk++) af[kk] = *(const short8*)(qa + kk * 32 + kg * 8);
  af[16] = *(const short8*)(qptr + kg * 8);
  af[17] = *(const short8*)(qptr + 32 + kg * 8);

  short8 ones;
#pragma unroll
  for (int jj = 0; jj < 8; jj++) ones[jj] = (short)0x3F80;   // bf16 1.0

  const float4_t zero = {0.f, 0.f, 0.f, 0.f};
  float4_t oacc[33];                       // [32] = row-sum accumulator
#pragma unroll
  for (int nc = 0; nc < 33; nc++) oacc[nc] = zero;
  float mrow[4] = {-1e30f, -1e30f, -1e30f, -1e30f};   // log2-domain running max

  const ushort_t* kfb = Kf + (long)b * (128 * 18 * 512);
  const ushort_t* vfb = Vf + (long)b * (64 * 32 * 512);
  const int nt = (wq0 + 16 + 31) >> 5;

  // stage tile: 68 chunks of 1KB; wave handles chunks w, w+8, ...
  auto stage = [&](int tile) {
    const ushort_t* ks = kfb + (long)(tile * 2) * (18 * 512);
    const ushort_t* vs = vfb + (long)tile * (32 * 512);
#pragma unroll
    for (int i = 0; i < 9; i++) {
      int c = w + i * 8;
      if (c < 68) {
        const ushort_t* src = (c < 36) ? (ks + c * 512) : (vs + (c - 36) * 512);
        gload16(src + l * 8, &KV[c * 512]);
      }
    }
  };

  for (int tile = 0; tile < nt; tile++) {
    stage(tile);
    __syncthreads();                      // staged writes visible to all waves
    const int t0 = tile * 32;

    // ---- QK^T from LDS (linear ds_read_b128) ----
    float4_t sc[2] = {zero, zero};
#pragma unroll
    for (int nf = 0; nf < 2; nf++)
#pragma unroll
      for (int kk = 0; kk < 18; kk++) {
        short8 bfr = *(const short8*)(&KV[(nf * 18 + kk) * 512 + l * 8]);
        sc[nf] = __builtin_amdgcn_mfma_f32_16x16x32_bf16(af[kk], bfr, sc[nf], 0, 0, 0);
      }

    // ---- scale (log2 domain) + causal mask (only tail tiles) ----
    float pm[2][4];
    const bool tail = (t0 + 31 > wq0);
#pragma unroll
    for (int nf = 0; nf < 2; nf++)
#pragma unroll
      for (int r = 0; r < 4; r++) {
        float vv = sc[nf][r] * scale2;
        if (tail) {
          int tg = t0 + nf * 16 + fr;
          int qg = wq0 + kg * 4 + r;
          vv = (tg <= qg) ? vv : -1e30f;
        }
        pm[nf][r] = vv;
      }

    // ---- lazy online softmax: vote, reduce only on trigger (THR = 11.5416 bits) ----
    bool over = false;
#pragma unroll
    for (int nf = 0; nf < 2; nf++)
#pragma unroll
      for (int r = 0; r < 4; r++) over |= (pm[nf][r] > mrow[r] + 11.5416f);

    if (__any(over)) {                    // rare: full reduce + rescale
#pragma unroll
      for (int r = 0; r < 4; r++) {
        float tm = fmaxf(pm[0][r], pm[1][r]);
#pragma unroll
        for (int offx = 1; offx <= 8; offx <<= 1) tm = fmaxf(tm, __shfl_xor(tm, offx, 16));
        float mnew = fmaxf(mrow[r], tm);
        float alpha = exp2f(mrow[r] - mnew);
        mrow[r] = mnew;
#pragma unroll
        for (int nc = 0; nc < 33; nc++) oacc[nc][r] *= alpha;
      }
    }

#pragma unroll
    for (int r = 0; r < 4; r++) {
      float p0 = exp2f(pm[0][r] - mrow[r]);
      float p1 = exp2f(pm[1][r] - mrow[r]);
      Pl[w][(kg * 4 + r) * 40 + fr]      = f2b(p0);
      Pl[w][(kg * 4 + r) * 40 + 16 + fr] = f2b(p1);
    }

    // ---- PV from LDS V-chunks + fused row-sum ----
    short8 pa = *(const short8*)&Pl[w][fr * 40 + kg * 8];
#pragma unroll
    for (int nc = 0; nc < 32; nc++) {
      short8 bv = *(const short8*)(&KV[(36 + nc) * 512 + l * 8]);
      oacc[nc] = __builtin_amdgcn_mfma_f32_16x16x32_bf16(pa, bv, oacc[nc], 0, 0, 0);
    }
    oacc[32] = __builtin_amdgcn_mfma_f32_16x16x32_bf16(pa, ones, oacc[32], 0, 0, 0);

    __syncthreads();                      // all reads done before next stage overwrites
  }

  // ---- epilogue: LDS transpose -> coalesced O stores ----
  float invl[4];
#pragma unroll
  for (int r = 0; r < 4; r++) invl[r] = 1.f / oacc[32][r];
  ushort_t* KV0 = &KV[0];
  ushort_t* obase = O + ((long)h * MM + (long)b * SS + wq0) * CKV;
#pragma unroll
  for (int hh = 0; hh < 2; hh++) {
    __syncthreads();
#pragma unroll
    for (int nc2 = 0; nc2 < 16; nc2++) {
      int nc = hh * 16 + nc2;
#pragma unroll
      for (int r = 0; r < 4; r++)
        KV0[w * 4096 + (kg * 4 + r) * 256 + nc2 * 16 + fr] = f2b(oacc[nc][r] * invl[r]);
    }
    __syncthreads();
#pragma unroll
    for (int i = 0; i < 8; i++) {
      short8 vv = *(const short8*)&KV0[w * 4096 + i * 512 + l * 8];
      int row = 2 * i + (l >> 5);
      int col = (l & 31) * 8;
      *(short8*)(obase + (long)row * CKV + hh * 256 + col) = vv;
    }
  }
}

// ---------------- launch ----------------
extern "C" void kernel_launch(void* const* d_in, const int* in_sizes, int n_in,
                              void* d_out, int out_size, void* d_ws, size_t ws_size,
                              hipStream_t stream) {
  const float* x    = (const float*)d_in[0];
  const float* fcos = (const float*)d_in[2];
  const float* fsin = (const float*)d_in[3];
  const float* wq   = (const float*)d_in[4];
  const float* wkva = (const float*)d_in[5];
  const float* kvw  = (const float*)d_in[6];
  const float* wkvb = (const float*)d_in[7];
  const float* wo   = (const float*)d_in[8];
  float* out = (float*)d_out;
  char* ws = (char*)d_ws;

  const size_t O_WCAT = 0;
  const size_t O_WBT  = O_WCAT + (size_t)NPAD * DIM * 2;
  const size_t O_WBV  = O_WBT + (size_t)HH * CKV * DN * 2;
  const size_t O_WO   = O_WBV + (size_t)HH * DN * CKV * 2;
  const size_t O_KEXT = O_WO + (size_t)DIM * DIM * 2;
  const size_t O_QABS = O_KEXT + (size_t)MM * 576 * 2;
  const size_t O_QPE  = O_QABS + (size_t)HH * MM * CKV * 2;
  const size_t O_O2   = O_QPE + (size_t)HH * MM * DR * 2;
  const size_t O_T    = O_O2 + (size_t)MM * DIM * 2;
  const size_t O_Y    = O_T + (size_t)MM * DIM * 2;

  const size_t KF_BYTES = (size_t)BB * 128 * 18 * 512 * 2;   // 4.72 MB

  ushort_t* wcat  = (ushort_t*)(ws + O_WCAT);
  ushort_t* kf    = (ushort_t*)(ws + O_WCAT);              // overlays wcat (dead after G1)
  ushort_t* vf    = (ushort_t*)(ws + O_WCAT + KF_BYTES);   // overlays wcat too
  ushort_t* wbT   = (ushort_t*)(ws + O_WBT);
  ushort_t* wbv   = (ushort_t*)(ws + O_WBV);
  ushort_t* wo_b  = (ushort_t*)(ws + O_WO);
  ushort_t* kext  = (ushort_t*)(ws + O_KEXT);
  ushort_t* qabs  = (ushort_t*)(ws + O_QABS);
  ushort_t* qpe   = (ushort_t*)(ws + O_QPE);
  ushort_t* o2    = (ushort_t*)(ws + O_O2);
  ushort_t* xb    = (ushort_t*)(ws + O_T);      // transient
  ushort_t* qnope = (ushort_t*)(ws + O_T);      // reuses xb
  ushort_t* oatt  = (ushort_t*)(ws + O_T);      // reuses xb+Y
  ushort_t* Y     = (ushort_t*)(ws + O_Y);

  double msc = 0.1 * log(40.0) + 1.0;
  float scale = (float)(pow((double)QKH, -0.5) * msc * msc);
  float scale2 = scale * 1.4426950408889634f;   // log2(e) folded in

  dim3 blk(256);
  f32_to_bf16_k<<<dim3(4096), blk, 0, stream>>>(x, xb, (long)MM * DIM);
  build_wcat_k<<<dim3(4096), blk, 0, stream>>>(wq, wkva, wcat);
  build_wb_k<<<dim3(1024), blk, 0, stream>>>(wkvb, wbT, wbv);
  f32_to_bf16_k<<<dim3(2048), blk, 0, stream>>>(wo, wo_b, (long)DIM * DIM);

  // G1: Y = x @ [wq; wkv_a]^T
  gemm_bt<ushort_t><<<dim3(32, 29, 1), blk, 0, stream>>>(
      xb, wcat, Y, DIM, DIM, DIM, NPAD, 0, 0, 0);

  postproc_k<<<dim3(MM), blk, 0, stream>>>(Y, fcos, fsin, kvw, qnope, qpe, kext);

  // fragment-retile K and V (overlay dead wcat)
  retile_k_k<<<dim3(288), blk, 0, stream>>>(kext, kf);
  transpose_vf_k<<<dim3(SS / 64, CKV / 64, BB), blk, 0, stream>>>(kext, vf);

  // G2: qabs[h] = qnope[h] @ wbT[h]^T
  gemm_bt<ushort_t><<<dim3(32, 4, HH), blk, 0, stream>>>(
      qnope, wbT, qabs, DN, DN, DN, CKV,
      (long)MM * DN, (long)CKV * DN, (long)MM * CKV);

  attn11_k<<<dim3(256, 2), dim3(512), 0, stream>>>(qabs, qpe, kf, vf, oatt, scale2);

  // G4
  gemm_bt<ushort_t><<<dim3(32, 1, HH), blk, 0, stream>>>(
      oatt, wbv, o2, CKV, CKV, CKV, DIM,
      (long)MM * CKV, (long)DN * CKV, (long)DN);

  // G5
  gemm_bt<float><<<dim3(32, 16, 1), blk, 0, stream>>>(
      o2, wo_b, out, DIM, DIM, DIM, DIM, 0, 0, 0);
}